// Round 6
// baseline (253.971 us; speedup 1.0000x reference)
//
#include <hip/hip_runtime.h>
#include <hip/hip_bf16.h>
#include <math.h>

// QANet Context-Query attention. B=32 H=128 C=2048 Q=256.
// R5: (1) k_T2 -> bf16 MFMA (transposed-E LDS staging, ctxB bf16 operand
//     emitted by k_partc); (2) k_rowstats+k_colpart fused into k_stats which
//     also writes RN (row-normalized S) as bf16; (3) k_out_mfma reads RNb
//     directly (no exp / rowstats). Tpart/ctxW/qT scratch in d_out.

constexpr int kB = 32, kH = 128, kC = 2048, kQ = 256;
constexpr int kColChunks = 128;          // 32 i-chunks x 4 waves
constexpr float kNEG = -1e30f;

typedef short bf16x8 __attribute__((ext_vector_type(8)));
typedef float f32x4 __attribute__((ext_vector_type(4)));

static __device__ __forceinline__ unsigned short f2bf(float f) {
    __hip_bfloat16 h = __float2bfloat16(f);
    return __builtin_bit_cast(unsigned short, h);
}

// part_c[b,i] = sum_h ctx*w_c; also emits ctxB = bf16(ctx) in [b,h,i] layout.
__global__ __launch_bounds__(256) void k_partc(const float* __restrict__ ctx,
                                               const float* __restrict__ w_c,
                                               float* __restrict__ part_c,
                                               unsigned short* __restrict__ ctxB) {
    int id = blockIdx.x * 256 + threadIdx.x;   // over B*C
    int b = id / kC, i = id % kC;
    float acc = 0.f;
#pragma unroll 8
    for (int h = 0; h < kH; ++h) {
        float v = ctx[((size_t)b * kH + h) * kC + i];
        acc += v * w_c[h];
        ctxB[((size_t)b * kH + h) * kC + i] = f2bf(v);
    }
    part_c[id] = acc;
}

__global__ __launch_bounds__(256) void k_partq(const float* __restrict__ q,
                                               const float* __restrict__ w_q,
                                               float* __restrict__ part_q) {
    int id = blockIdx.x * 256 + threadIdx.x;   // over B*Q
    int b = id / kQ, j = id % kQ;
    float acc = 0.f;
#pragma unroll 8
    for (int h = 0; h < kH; ++h)
        acc += q[((size_t)b * kH + h) * kQ + j] * w_q[h];
    part_q[id] = acc;
}

// Transpose ctx [b,h,i] -> ctxW bf16 [b,i,h], scaled by w_cq[h].
__global__ __launch_bounds__(256) void k_trc(const float* __restrict__ ctx,
                                             const float* __restrict__ w_cq,
                                             unsigned short* __restrict__ ctxW) {
    int i0 = blockIdx.x * 64, b = blockIdx.y;
    __shared__ unsigned short tile[64 * 136];
    int t = threadIdx.x;
    int il = t & 63;
    int hb = (t >> 6) * 2;
#pragma unroll
    for (int r = 0; r < 16; ++r) {
        int h = r * 8 + hb;
        float v0 = ctx[((size_t)b * kH + h) * kC + i0 + il] * w_cq[h];
        float v1 = ctx[((size_t)b * kH + h + 1) * kC + i0 + il] * w_cq[h + 1];
        unsigned int pk = (unsigned int)f2bf(v0) | ((unsigned int)f2bf(v1) << 16);
        *(unsigned int*)&tile[il * 136 + h] = pk;
    }
    __syncthreads();
#pragma unroll
    for (int r = 0; r < 4; ++r) {
        int idx = r * 256 + t;
        int i = idx >> 4, hc = (idx & 15) * 8;
        *(bf16x8*)&ctxW[((size_t)b * kC + i0 + i) * kH + hc] =
            *(const bf16x8*)&tile[i * 136 + hc];
    }
}

// Transpose q [b,h,j] -> qT bf16 [b,j,h].
__global__ __launch_bounds__(256) void k_trq(const float* __restrict__ q,
                                             unsigned short* __restrict__ qT) {
    int j0 = blockIdx.x * 64, b = blockIdx.y;
    __shared__ unsigned short tile[64 * 136];
    int t = threadIdx.x;
    int jl = t & 63;
    int hb = (t >> 6) * 2;
#pragma unroll
    for (int r = 0; r < 16; ++r) {
        int h = r * 8 + hb;
        float v0 = q[((size_t)b * kH + h) * kQ + j0 + jl];
        float v1 = q[((size_t)b * kH + h + 1) * kQ + j0 + jl];
        unsigned int pk = (unsigned int)f2bf(v0) | ((unsigned int)f2bf(v1) << 16);
        *(unsigned int*)&tile[jl * 136 + h] = pk;
    }
    __syncthreads();
#pragma unroll
    for (int r = 0; r < 4; ++r) {
        int idx = r * 256 + t;
        int j = idx >> 4, hc = (idx & 15) * 8;
        *(bf16x8*)&qT[((size_t)b * kQ + j0 + j) * kH + hc] =
            *(const bf16x8*)&tile[j * 136 + hc];
    }
}

// S via MFMA: S[b,i,j] = ctxW[b,i,:] . qT[b,j,:] + part_c + part_q + bias.
__global__ __launch_bounds__(256) void k_S_mfma(const unsigned short* __restrict__ ctxW,
                                                const unsigned short* __restrict__ qT,
                                                const float* __restrict__ part_c,
                                                const float* __restrict__ part_q,
                                                const float* __restrict__ bias,
                                                float* __restrict__ S) {
    int i0 = blockIdx.x * 128, j0 = blockIdx.y * 128, b = blockIdx.z;
    __shared__ unsigned short As[128 * 40];
    __shared__ unsigned short Bs[128 * 40];
    int t = threadIdx.x;
    int lane = t & 63, wave = t >> 6;
    int wm = wave >> 1, wn = wave & 1;
    int lrow = lane & 15, kgrp = (lane >> 4) * 8;

    f32x4 acc[4][4];
#pragma unroll
    for (int mt = 0; mt < 4; ++mt)
#pragma unroll
        for (int nt = 0; nt < 4; ++nt)
            acc[mt][nt] = (f32x4){0.f, 0.f, 0.f, 0.f};

    for (int kk = 0; kk < 4; ++kk) {
        int h0 = kk * 32;
#pragma unroll
        for (int r = 0; r < 2; ++r) {
            int idx = r * 256 + t;
            int i = idx >> 2, hc = (idx & 3) * 8;
            *(bf16x8*)&As[i * 40 + hc] =
                *(const bf16x8*)&ctxW[((size_t)b * kC + i0 + i) * kH + h0 + hc];
            *(bf16x8*)&Bs[i * 40 + hc] =
                *(const bf16x8*)&qT[((size_t)b * kQ + j0 + i) * kH + h0 + hc];
        }
        __syncthreads();
        bf16x8 af[4], bf[4];
#pragma unroll
        for (int mt = 0; mt < 4; ++mt)
            af[mt] = *(const bf16x8*)&As[(wm * 64 + mt * 16 + lrow) * 40 + kgrp];
#pragma unroll
        for (int nt = 0; nt < 4; ++nt)
            bf[nt] = *(const bf16x8*)&Bs[(wn * 64 + nt * 16 + lrow) * 40 + kgrp];
#pragma unroll
        for (int nt = 0; nt < 4; ++nt)
#pragma unroll
            for (int mt = 0; mt < 4; ++mt)
                acc[mt][nt] = __builtin_amdgcn_mfma_f32_16x16x32_bf16(af[mt], bf[nt], acc[mt][nt], 0, 0, 0);
        __syncthreads();
    }

    float bs = bias[0];
    float pq[4];
#pragma unroll
    for (int nt = 0; nt < 4; ++nt)
        pq[nt] = part_q[b * kQ + j0 + wn * 64 + nt * 16 + lrow];
#pragma unroll
    for (int mt = 0; mt < 4; ++mt)
#pragma unroll
        for (int r = 0; r < 4; ++r) {
            int i = i0 + wm * 64 + mt * 16 + (lane >> 4) * 4 + r;
            float pc = part_c[b * kC + i] + bs;
            float* dst = S + ((size_t)b * kC + i) * kQ + j0 + wn * 64 + lrow;
#pragma unroll
            for (int nt = 0; nt < 4; ++nt)
                dst[nt * 16] = acc[mt][nt][r] + pc + pq[nt];
        }
}

// Fused stats: one pass over S per 64-row chunk. Each wave: 16 rows.
// Row softmax (qmask): max+sum via shuffles, writes RN bf16.
// Col partials (cmask): online (m,s) per lane-column, 128 wave-chunks.
__global__ __launch_bounds__(256) void k_stats(const float* __restrict__ S,
                                               const int* __restrict__ qmask,
                                               const int* __restrict__ cmask,
                                               unsigned short* __restrict__ RNb,
                                               float* __restrict__ pm,
                                               float* __restrict__ ps) {
    int chunk = blockIdx.x, b = blockIdx.y;
    int t = threadIdx.x, lane = t & 63, w = t >> 6;
    int qmv[4];
    float cm[4], cs[4];
#pragma unroll
    for (int m = 0; m < 4; ++m) {
        qmv[m] = qmask[b * kQ + lane + m * 64];
        cm[m] = kNEG;
        cs[m] = 0.f;
    }
    int ibase = chunk * 64 + w * 16;
    for (int rr = 0; rr < 16; ++rr) {
        int i = ibase + rr;
        const float* row = S + ((size_t)b * kC + i) * kQ;
        float raw[4];
        float rmax = kNEG;
#pragma unroll
        for (int m = 0; m < 4; ++m) {
            raw[m] = row[lane + m * 64];
            rmax = fmaxf(rmax, qmv[m] ? raw[m] : kNEG);
        }
        for (int off = 32; off; off >>= 1) rmax = fmaxf(rmax, __shfl_xor(rmax, off));
        float e[4], rsum = 0.f;
#pragma unroll
        for (int m = 0; m < 4; ++m) {
            e[m] = qmv[m] ? __expf(raw[m] - rmax) : 0.f;
            rsum += e[m];
        }
        for (int off = 32; off; off >>= 1) rsum += __shfl_xor(rsum, off);
        float rinv = 1.f / rsum;
        unsigned short* dst = RNb + ((size_t)b * kC + i) * kQ;
#pragma unroll
        for (int m = 0; m < 4; ++m)
            dst[lane + m * 64] = f2bf(e[m] * rinv);
        if (cmask[b * kC + i]) {
#pragma unroll
            for (int m = 0; m < 4; ++m) {
                float v = raw[m];
                if (v > cm[m]) { cs[m] = cs[m] * __expf(cm[m] - v) + 1.f; cm[m] = v; }
                else           { cs[m] += __expf(v - cm[m]); }
            }
        }
    }
    int wc = chunk * 4 + w;
#pragma unroll
    for (int m = 0; m < 4; ++m) {
        pm[((size_t)b * kColChunks + wc) * kQ + lane + m * 64] = cm[m];
        ps[((size_t)b * kColChunks + wc) * kQ + lane + m * 64] = cs[m];
    }
}

__global__ __launch_bounds__(256) void k_colcombine(const float* __restrict__ pm,
                                                    const float* __restrict__ ps,
                                                    float* __restrict__ colmax,
                                                    float* __restrict__ colinv) {
    int id = blockIdx.x * 256 + threadIdx.x;   // over B*Q
    int b = id / kQ, j = id % kQ;
    float m = kNEG;
#pragma unroll 8
    for (int c = 0; c < kColChunks; ++c) m = fmaxf(m, pm[((size_t)b * kColChunks + c) * kQ + j]);
    float s = 0.f;
#pragma unroll 8
    for (int c = 0; c < kColChunks; ++c) {
        float pmv = pm[((size_t)b * kColChunks + c) * kQ + j];
        float psv = ps[((size_t)b * kColChunks + c) * kQ + j];
        if (pmv > -1e29f) s += psv * __expf(pmv - m);
    }
    colmax[id] = m;
    colinv[id] = 1.f / s;
}

// T partials via MFMA. Block (chunk of 256 i, jt of 128 j, b); D[h=128][j=128].
// A = ctxB[h][i] (K=i contig). B = E^T staged transposed into LDS:
// thread (ip=t>>4, js=t&15) covers i-pair {2ip,2ip+1} x j in {js+16m}, packed
// u32 writes at Et[j][2ip] -> banks (20*js+ip)%32 cover all 32 (2-way, free).
__global__ __launch_bounds__(256) void k_T2_mfma(const float* __restrict__ S,
                                                 const unsigned short* __restrict__ ctxB,
                                                 const int* __restrict__ cmask,
                                                 const float* __restrict__ colmax,
                                                 float* __restrict__ Tpart) {
    int chunk = blockIdx.x, jt = blockIdx.y, b = blockIdx.z;
    int j0 = jt * 128;
    __shared__ unsigned short Et[128 * 40];   // [j][i] transposed exp tile
    __shared__ unsigned short Bs[128 * 40];   // [h][i] ctx bf16
    __shared__ float cmArr[128];
    __shared__ int smc[256];
    int t = threadIdx.x;
    if (t < 128) cmArr[t] = colmax[b * kQ + j0 + t];
    smc[t] = cmask[b * kC + chunk * 256 + t];
    int lane = t & 63, wave = t >> 6;
    int wm = wave >> 1, wn = wave & 1;
    int lrow = lane & 15, kgrp = (lane >> 4) * 8;
    int ip = t >> 4, js = t & 15;
    int hB = t >> 1, isegB = (t & 1) * 16;

    f32x4 acc[4][4];
#pragma unroll
    for (int mt = 0; mt < 4; ++mt)
#pragma unroll
        for (int nt = 0; nt < 4; ++nt)
            acc[mt][nt] = (f32x4){0.f, 0.f, 0.f, 0.f};
    __syncthreads();

    for (int kk = 0; kk < 8; ++kk) {
        int i0 = chunk * 256 + kk * 32;
        int li = kk * 32 + 2 * ip;
        bool v0ok = smc[li] != 0, v1ok = smc[li + 1] != 0;
        const float* s0 = S + ((size_t)b * kC + i0 + 2 * ip) * kQ + j0;
#pragma unroll
        for (int m = 0; m < 8; ++m) {
            int j = js + 16 * m;
            float cmj = cmArr[j];
            float e0 = v0ok ? __expf(s0[j] - cmj) : 0.f;
            float e1 = v1ok ? __expf(s0[kQ + j] - cmj) : 0.f;
            unsigned int pk = (unsigned int)f2bf(e0) | ((unsigned int)f2bf(e1) << 16);
            *(unsigned int*)&Et[j * 40 + 2 * ip] = pk;
        }
        {
            const unsigned short* cb = ctxB + ((size_t)b * kH + hB) * kC + i0 + isegB;
            *(bf16x8*)&Bs[hB * 40 + isegB]     = *(const bf16x8*)cb;
            *(bf16x8*)&Bs[hB * 40 + isegB + 8] = *(const bf16x8*)(cb + 8);
        }
        __syncthreads();
        bf16x8 af[4], bf[4];
#pragma unroll
        for (int mt = 0; mt < 4; ++mt)
            af[mt] = *(const bf16x8*)&Bs[(wm * 64 + mt * 16 + lrow) * 40 + kgrp];
#pragma unroll
        for (int nt = 0; nt < 4; ++nt)
            bf[nt] = *(const bf16x8*)&Et[(wn * 64 + nt * 16 + lrow) * 40 + kgrp];
#pragma unroll
        for (int nt = 0; nt < 4; ++nt)
#pragma unroll
            for (int mt = 0; mt < 4; ++mt)
                acc[mt][nt] = __builtin_amdgcn_mfma_f32_16x16x32_bf16(af[mt], bf[nt], acc[mt][nt], 0, 0, 0);
        __syncthreads();
    }

    const size_t M = (size_t)kB * kH * kQ;
#pragma unroll
    for (int mt = 0; mt < 4; ++mt)
#pragma unroll
        for (int r = 0; r < 4; ++r) {
            int h = wm * 64 + mt * 16 + (lane >> 4) * 4 + r;
            float* dst = Tpart + (size_t)chunk * M + ((size_t)b * kH + h) * kQ + j0 + wn * 64 + lrow;
#pragma unroll
            for (int nt = 0; nt < 4; ++nt)
                dst[nt * 16] = acc[mt][nt][r];
        }
}

// T_bf16[b,h,j] = bf16( colinv[b,j] * sum_chunk Tpart[chunk][b,h,j] )
__global__ __launch_bounds__(256) void k_Tred(const float* __restrict__ Tpart,
                                              const float* __restrict__ colinv,
                                              unsigned short* __restrict__ Tb) {
    size_t id = (size_t)blockIdx.x * 256 + threadIdx.x;   // over B*H*Q
    const size_t M = (size_t)kB * kH * kQ;
    int j = (int)(id % kQ);
    int b = (int)(id / ((size_t)kH * kQ));
    float s = 0.f;
#pragma unroll
    for (int c = 0; c < 8; ++c) s += Tpart[c * M + id];
    Tb[id] = f2bf(s * colinv[b * kQ + j]);
}

// MFMA output kernel: 64 i x 128 h per block; A = RNb (precomputed bf16).
__global__ __launch_bounds__(256) void k_out_mfma(const unsigned short* __restrict__ RNb,
                                                  const float* __restrict__ q,
                                                  const unsigned short* __restrict__ Tb,
                                                  const float* __restrict__ ctx,
                                                  float* __restrict__ out) {
    int i0 = blockIdx.x * 64;
    int b  = blockIdx.y;
    __shared__ unsigned short As[64 * 40];
    __shared__ unsigned short qs[128 * 40];
    __shared__ unsigned short ts[128 * 40];
    __shared__ float stg[128 * 67];
    int t = threadIdx.x;

    int rA = t >> 2, cA = (t & 3) * 8;
    int rq = t >> 1, cq = (t & 1) * 16;

    int lane = t & 63, wave = t >> 6;
    int hw = wave * 32;
    int kgrp = (lane >> 4) * 8;
    int lrow = lane & 15;

    f32x4 accC[4][2];
    f32x4 accT[4][2];
#pragma unroll
    for (int mt = 0; mt < 4; ++mt)
#pragma unroll
        for (int nt = 0; nt < 2; ++nt) {
            accC[mt][nt] = (f32x4){0.f, 0.f, 0.f, 0.f};
            accT[mt][nt] = (f32x4){0.f, 0.f, 0.f, 0.f};
        }

    for (int kk = 0; kk < 8; ++kk) {
        int j0 = kk * 32;
        *(bf16x8*)&As[rA * 40 + cA] =
            *(const bf16x8*)&RNb[((size_t)b * kC + i0 + rA) * kQ + j0 + cA];
        {   // q fp32 -> bf16
            const float* src = q + ((size_t)b * kH + rq) * kQ + j0 + cq;
            float4 a0 = *(const float4*)src;
            float4 a1 = *(const float4*)(src + 4);
            float4 a2 = *(const float4*)(src + 8);
            float4 a3 = *(const float4*)(src + 12);
            float vv[16] = {a0.x, a0.y, a0.z, a0.w, a1.x, a1.y, a1.z, a1.w,
                            a2.x, a2.y, a2.z, a2.w, a3.x, a3.y, a3.z, a3.w};
            bf16x8 p0, p1;
#pragma unroll
            for (int e = 0; e < 8; ++e) {
                p0[e] = (short)f2bf(vv[e]);
                p1[e] = (short)f2bf(vv[8 + e]);
            }
            *(bf16x8*)&qs[rq * 40 + cq] = p0;
            *(bf16x8*)&qs[rq * 40 + cq + 8] = p1;
        }
        {   // T bf16 direct copy
            const unsigned short* src = Tb + ((size_t)b * kH + rq) * kQ + j0 + cq;
            *(bf16x8*)&ts[rq * 40 + cq]     = *(const bf16x8*)src;
            *(bf16x8*)&ts[rq * 40 + cq + 8] = *(const bf16x8*)(src + 8);
        }
        __syncthreads();
        bf16x8 af[4];
#pragma unroll
        for (int mt = 0; mt < 4; ++mt)
            af[mt] = *(const bf16x8*)&As[(mt * 16 + lrow) * 40 + kgrp];
#pragma unroll
        for (int nt = 0; nt < 2; ++nt) {
            bf16x8 bq = *(const bf16x8*)&qs[(hw + nt * 16 + lrow) * 40 + kgrp];
            bf16x8 bt = *(const bf16x8*)&ts[(hw + nt * 16 + lrow) * 40 + kgrp];
#pragma unroll
            for (int mt = 0; mt < 4; ++mt) {
                accC[mt][nt] = __builtin_amdgcn_mfma_f32_16x16x32_bf16(af[mt], bq, accC[mt][nt], 0, 0, 0);
                accT[mt][nt] = __builtin_amdgcn_mfma_f32_16x16x32_bf16(af[mt], bt, accT[mt][nt], 0, 0, 0);
            }
        }
        __syncthreads();
    }

    const size_t N = (size_t)kB * kH * kC;
    int ii = t & 63, hb = t >> 6;
#pragma unroll
    for (int mt = 0; mt < 4; ++mt)
#pragma unroll
        for (int nt = 0; nt < 2; ++nt)
#pragma unroll
            for (int r = 0; r < 4; ++r)
                stg[(hw + nt * 16 + lrow) * 67 + mt * 16 + (lane >> 4) * 4 + r] = accC[mt][nt][r];
    __syncthreads();
#pragma unroll 4
    for (int p = 0; p < 32; ++p) {
        int h = hb + p * 4;
        float v = stg[h * 67 + ii];
        size_t base = ((size_t)b * kH + h) * kC + i0 + ii;
        float c = ctx[base];
        out[base]         = c;
        out[N + base]     = v;
        out[2 * N + base] = c * v;
    }
    __syncthreads();
#pragma unroll
    for (int mt = 0; mt < 4; ++mt)
#pragma unroll
        for (int nt = 0; nt < 2; ++nt)
#pragma unroll
            for (int r = 0; r < 4; ++r)
                stg[(hw + nt * 16 + lrow) * 67 + mt * 16 + (lane >> 4) * 4 + r] = accT[mt][nt][r];
    __syncthreads();
#pragma unroll 4
    for (int p = 0; p < 32; ++p) {
        int h = hb + p * 4;
        float v = stg[h * 67 + ii];
        size_t base = ((size_t)b * kH + h) * kC + i0 + ii;
        float c = ctx[base];
        out[3 * N + base] = c * v;
    }
}

extern "C" void kernel_launch(void* const* d_in, const int* in_sizes, int n_in,
                              void* d_out, int out_size, void* d_ws, size_t ws_size,
                              hipStream_t stream) {
    const float* ctx   = (const float*)d_in[0];
    const float* q     = (const float*)d_in[1];
    const int*   cmask = (const int*)d_in[2];
    const int*   qmask = (const int*)d_in[3];
    const float* w_c   = (const float*)d_in[4];
    const float* w_q   = (const float*)d_in[5];
    const float* w_cq  = (const float*)d_in[6];
    const float* bias  = (const float*)d_in[7];
    float* out = (float*)d_out;

    // Workspace layout (~130 MB; ws is 512 MiB).
    float* ws = (float*)d_ws;
    float* S            = ws;                                           // B*C*Q f32
    unsigned short* RNb = (unsigned short*)(S + (size_t)kB * kC * kQ);  // B*C*Q bf16
    unsigned short* Tb  = RNb + (size_t)kB * kC * kQ;                   // B*H*Q bf16
    unsigned short* ctxB = Tb + (size_t)kB * kH * kQ;                   // B*H*C bf16
    float* part_c = (float*)(ctxB + (size_t)kB * kH * kC);              // B*C
    float* part_q = part_c + kB * kC;                                   // B*Q
    float* colmax = part_q + kB * kQ;                                   // B*Q
    float* colinv = colmax + kB * kQ;                                   // B*Q
    float* pm     = colinv + kB * kQ;                                   // B*128*Q
    float* ps     = pm + (size_t)kB * kColChunks * kQ;                  // B*128*Q
    size_t need = (size_t)((char*)(ps + (size_t)kB * kColChunks * kQ) - (char*)ws);
    if (ws_size < need) return;

    // d_out scratch (all overwritten by k_out_mfma):
    //   [0, N) floats        : Tpart (8 * B*H*Q f32)
    //   [2N, 2.5N) floats    : ctxW  (B*C*H bf16)
    //   then qT              : (B*Q*H bf16)
    const size_t N = (size_t)kB * kH * kC;
    float* Tpart = out;
    unsigned short* ctxW = (unsigned short*)(out + 2 * N);
    unsigned short* qT   = ctxW + (size_t)kB * kC * kH;

    k_partc<<<kB * kC / 256, 256, 0, stream>>>(ctx, w_c, part_c, ctxB);
    k_partq<<<kB * kQ / 256, 256, 0, stream>>>(q, w_q, part_q);
    k_trc<<<dim3(kC / 64, kB), 256, 0, stream>>>(ctx, w_cq, ctxW);
    k_trq<<<dim3(kQ / 64, kB), 256, 0, stream>>>(q, qT);
    k_S_mfma<<<dim3(kC / 128, kQ / 128, kB), 256, 0, stream>>>(ctxW, qT, part_c, part_q, bias, S);
    k_stats<<<dim3(kC / 64, kB), 256, 0, stream>>>(S, qmask, cmask, RNb, pm, ps);
    k_colcombine<<<kB * kQ / 256, 256, 0, stream>>>(pm, ps, colmax, colinv);
    k_T2_mfma<<<dim3(8, 2, kB), 256, 0, stream>>>(S, ctxB, cmask, colmax, Tpart);
    k_Tred<<<kB * kH * kQ / 256, 256, 0, stream>>>(Tpart, colinv, Tb);
    k_out_mfma<<<dim3(kC / 64, kB), 256, 0, stream>>>(RNb, q, Tb, ctx, out);
}

// Round 7
// 192.313 us; speedup vs baseline: 1.3206x; 1.3206x over previous
//
#include <hip/hip_runtime.h>
#include <hip/hip_bf16.h>
#include <math.h>

// QANet Context-Query attention. B=32 H=128 C=2048 Q=256.
// R6: S fp32 eliminated. k_Ssoft = S-GEMM + in-register row-softmax (writes
//     RNb bf16 + rowscale) + online col-partials. T path reconstructs
//     exp(S-colmax) = RN * rowscale_i * colscale_j (no exp in staging).
//     prep kernels fuse transpose+bf16-cast+part sums (one read of ctx/q).
//     out_mfma: direct-global B fragments (qB/Tb), single-ctx-read epilogue.

constexpr int kB = 32, kH = 128, kC = 2048, kQ = 256;
constexpr int kColChunks = 128;          // (kC/64) blocks * 4 waves
constexpr float kNEG = -1e30f;

typedef short bf16x8 __attribute__((ext_vector_type(8)));
typedef float f32x4 __attribute__((ext_vector_type(4)));

static __device__ __forceinline__ unsigned short f2bf(float f) {
    __hip_bfloat16 h = __float2bfloat16(f);
    return __builtin_bit_cast(unsigned short, h);
}
static __device__ __forceinline__ float bf2f(unsigned short u) {
    unsigned int x = ((unsigned int)u) << 16;
    return __builtin_bit_cast(float, x);
}

// One ctx read -> ctxW[b,i,h]=bf16(ctx*w_cq), ctxB[b,h,i]=bf16(ctx), part_c.
__global__ __launch_bounds__(256) void k_prep_c(const float* __restrict__ ctx,
                                                const float* __restrict__ w_c,
                                                const float* __restrict__ w_cq,
                                                unsigned short* __restrict__ ctxW,
                                                unsigned short* __restrict__ ctxB,
                                                float* __restrict__ part_c) {
    int i0 = blockIdx.x * 64, b = blockIdx.y;
    __shared__ unsigned short tile[64 * 136];
    __shared__ float pcp[4][64];
    int t = threadIdx.x;
    int il = t & 63, hg = t >> 6, hb = hg * 2;
    float accc = 0.f;
#pragma unroll
    for (int r = 0; r < 16; ++r) {
        int h = r * 8 + hb;
        float v0 = ctx[((size_t)b * kH + h) * kC + i0 + il];
        float v1 = ctx[((size_t)b * kH + h + 1) * kC + i0 + il];
        accc += v0 * w_c[h] + v1 * w_c[h + 1];
        ctxB[((size_t)b * kH + h) * kC + i0 + il]     = f2bf(v0);
        ctxB[((size_t)b * kH + h + 1) * kC + i0 + il] = f2bf(v1);
        unsigned int pk = (unsigned int)f2bf(v0 * w_cq[h]) |
                          ((unsigned int)f2bf(v1 * w_cq[h + 1]) << 16);
        *(unsigned int*)&tile[il * 136 + h] = pk;
    }
    pcp[hg][il] = accc;
    __syncthreads();
    if (t < 64) part_c[b * kC + i0 + t] = pcp[0][t] + pcp[1][t] + pcp[2][t] + pcp[3][t];
#pragma unroll
    for (int r = 0; r < 4; ++r) {
        int idx = r * 256 + t;
        int i = idx >> 4, hc = (idx & 15) * 8;
        *(bf16x8*)&ctxW[((size_t)b * kC + i0 + i) * kH + hc] =
            *(const bf16x8*)&tile[i * 136 + hc];
    }
}

// One q read -> qT[b,j,h]=bf16(q), qB[b,h,j]=bf16(q), part_q.
__global__ __launch_bounds__(256) void k_prep_q(const float* __restrict__ q,
                                                const float* __restrict__ w_q,
                                                unsigned short* __restrict__ qT,
                                                unsigned short* __restrict__ qB,
                                                float* __restrict__ part_q) {
    int j0 = blockIdx.x * 64, b = blockIdx.y;
    __shared__ unsigned short tile[64 * 136];
    __shared__ float pcp[4][64];
    int t = threadIdx.x;
    int jl = t & 63, hg = t >> 6, hb = hg * 2;
    float accq = 0.f;
#pragma unroll
    for (int r = 0; r < 16; ++r) {
        int h = r * 8 + hb;
        float v0 = q[((size_t)b * kH + h) * kQ + j0 + jl];
        float v1 = q[((size_t)b * kH + h + 1) * kQ + j0 + jl];
        accq += v0 * w_q[h] + v1 * w_q[h + 1];
        qB[((size_t)b * kH + h) * kQ + j0 + jl]     = f2bf(v0);
        qB[((size_t)b * kH + h + 1) * kQ + j0 + jl] = f2bf(v1);
        unsigned int pk = (unsigned int)f2bf(v0) | ((unsigned int)f2bf(v1) << 16);
        *(unsigned int*)&tile[jl * 136 + h] = pk;
    }
    pcp[hg][jl] = accq;
    __syncthreads();
    if (t < 64) part_q[b * kQ + j0 + t] = pcp[0][t] + pcp[1][t] + pcp[2][t] + pcp[3][t];
#pragma unroll
    for (int r = 0; r < 4; ++r) {
        int idx = r * 256 + t;
        int j = idx >> 4, hc = (idx & 15) * 8;
        *(bf16x8*)&qT[((size_t)b * kQ + j0 + j) * kH + hc] =
            *(const bf16x8*)&tile[j * 136 + hc];
    }
}

// Fused S + softmax. Block = 64 i x 256 j (full Q); wave = 16 i x 256 j.
// Writes RNb (row-normalized, qmasked, bf16), rowscale = rowsum*e^rowmax,
// and per-column online (max,sum) partials over cmask'd rows (chunk = 16 rows).
__global__ __launch_bounds__(256) void k_Ssoft(const unsigned short* __restrict__ ctxW,
                                               const unsigned short* __restrict__ qT,
                                               const float* __restrict__ part_c,
                                               const float* __restrict__ part_q,
                                               const float* __restrict__ bias,
                                               const int* __restrict__ qmask,
                                               const int* __restrict__ cmask,
                                               unsigned short* __restrict__ RNb,
                                               float* __restrict__ rowscale,
                                               float* __restrict__ pm,
                                               float* __restrict__ ps) {
    int i0 = blockIdx.x * 64, b = blockIdx.y;
    __shared__ unsigned short As[64 * 40];
    __shared__ unsigned short Bs[256 * 40];
    __shared__ float smpq[256];
    __shared__ int smqm[256];
    int t = threadIdx.x;
    int lane = t & 63, w = t >> 6;
    int lrow = lane & 15, q4 = lane >> 4, kgrp = q4 * 8;
    smpq[t] = part_q[b * kQ + t];
    smqm[t] = qmask[b * kQ + t];

    f32x4 acc[16];
#pragma unroll
    for (int nt = 0; nt < 16; ++nt) acc[nt] = (f32x4){0.f, 0.f, 0.f, 0.f};

    for (int kk = 0; kk < 4; ++kk) {
        int h0 = kk * 32;
        {
            int iA = t >> 2, hcA = (t & 3) * 8;
            *(bf16x8*)&As[iA * 40 + hcA] =
                *(const bf16x8*)&ctxW[((size_t)b * kC + i0 + iA) * kH + h0 + hcA];
        }
#pragma unroll
        for (int r2 = 0; r2 < 4; ++r2) {
            int idx = r2 * 256 + t;
            int jB = idx >> 2, hcB = (idx & 3) * 8;
            *(bf16x8*)&Bs[jB * 40 + hcB] =
                *(const bf16x8*)&qT[((size_t)b * kQ + jB) * kH + h0 + hcB];
        }
        __syncthreads();
        bf16x8 af = *(const bf16x8*)&As[(w * 16 + lrow) * 40 + kgrp];
#pragma unroll
        for (int nt = 0; nt < 16; ++nt) {
            bf16x8 bf = *(const bf16x8*)&Bs[(nt * 16 + lrow) * 40 + kgrp];
            acc[nt] = __builtin_amdgcn_mfma_f32_16x16x32_bf16(af, bf, acc[nt], 0, 0, 0);
        }
        __syncthreads();
    }

    // ---- epilogue: parts + row softmax + col partials ----
    float bs = bias[0];
    float pq[16];
    int qm[16];
#pragma unroll
    for (int nt = 0; nt < 16; ++nt) {
        int col = nt * 16 + lrow;
        pq[nt] = smpq[col];
        qm[nt] = smqm[col];
    }
    int rowbase = i0 + w * 16 + q4 * 4;
    float pc[4];
    int cmr[4];
#pragma unroll
    for (int r = 0; r < 4; ++r) {
        pc[r] = part_c[b * kC + rowbase + r] + bs;
        cmr[r] = cmask[b * kC + rowbase + r];
    }
#pragma unroll
    for (int nt = 0; nt < 16; ++nt)
#pragma unroll
        for (int r = 0; r < 4; ++r)
            acc[nt][r] += pc[r] + pq[nt];

    float cm[16], cs[16];
#pragma unroll
    for (int nt = 0; nt < 16; ++nt) { cm[nt] = kNEG; cs[nt] = 0.f; }

#pragma unroll
    for (int r = 0; r < 4; ++r) {
        float rmax = kNEG;
#pragma unroll
        for (int nt = 0; nt < 16; ++nt)
            if (qm[nt]) rmax = fmaxf(rmax, acc[nt][r]);
        rmax = fmaxf(rmax, __shfl_xor(rmax, 1));
        rmax = fmaxf(rmax, __shfl_xor(rmax, 2));
        rmax = fmaxf(rmax, __shfl_xor(rmax, 4));
        rmax = fmaxf(rmax, __shfl_xor(rmax, 8));
        float e[16];
        float rsum = 0.f;
#pragma unroll
        for (int nt = 0; nt < 16; ++nt) {
            e[nt] = qm[nt] ? __expf(acc[nt][r] - rmax) : 0.f;
            rsum += e[nt];
        }
        rsum += __shfl_xor(rsum, 1);
        rsum += __shfl_xor(rsum, 2);
        rsum += __shfl_xor(rsum, 4);
        rsum += __shfl_xor(rsum, 8);
        float rinv = 1.f / rsum;
        unsigned short* dst = RNb + ((size_t)b * kC + rowbase + r) * kQ;
#pragma unroll
        for (int nt = 0; nt < 16; ++nt)
            dst[nt * 16 + lrow] = f2bf(e[nt] * rinv);
        if (lrow == 0)
            rowscale[b * kC + rowbase + r] = rsum * __expf(rmax);
        // col partials on raw S, gated by cmask[row]
        if (cmr[r]) {
#pragma unroll
            for (int nt = 0; nt < 16; ++nt) {
                float v = acc[nt][r];
                float nm = fmaxf(cm[nt], v);
                cs[nt] = cs[nt] * __expf(cm[nt] - nm) + __expf(v - nm);
                cm[nt] = nm;
            }
        }
    }
    // combine col stats across the 4 lane-quarters (different rows, same cols)
#pragma unroll
    for (int off = 16; off <= 32; off <<= 1) {
#pragma unroll
        for (int nt = 0; nt < 16; ++nt) {
            float om = __shfl_xor(cm[nt], off);
            float os = __shfl_xor(cs[nt], off);
            float nm = fmaxf(cm[nt], om);
            cs[nt] = cs[nt] * __expf(cm[nt] - nm) + os * __expf(om - nm);
            cm[nt] = nm;
        }
    }
    int chunk = blockIdx.x * 4 + w;
#pragma unroll
    for (int k = 0; k < 4; ++k) {
        int nt = q4 * 4 + k;
        int col = nt * 16 + lrow;
        pm[((size_t)b * kColChunks + chunk) * kQ + col] = cm[nt];
        ps[((size_t)b * kColChunks + chunk) * kQ + col] = cs[nt];
    }
}

// colinv = 1/colsum, colscale = exp(-colmax).
__global__ __launch_bounds__(256) void k_colcombine(const float* __restrict__ pm,
                                                    const float* __restrict__ ps,
                                                    float* __restrict__ colscale,
                                                    float* __restrict__ colinv) {
    int id = blockIdx.x * 256 + threadIdx.x;   // over B*Q
    int b = id / kQ, j = id % kQ;
    float m = kNEG;
#pragma unroll 8
    for (int c = 0; c < kColChunks; ++c)
        m = fmaxf(m, pm[((size_t)b * kColChunks + c) * kQ + j]);
    float s = 0.f;
#pragma unroll 8
    for (int c = 0; c < kColChunks; ++c) {
        float pmv = pm[((size_t)b * kColChunks + c) * kQ + j];
        float psv = ps[((size_t)b * kColChunks + c) * kQ + j];
        if (pmv > -1e29f) s += psv * __expf(pmv - m);
    }
    colscale[id] = __expf(-m);
    colinv[id] = 1.f / s;
}

// T partials via MFMA. E[i,j] = cmask[i] ? RN[i,j]*rowscale[i]*colscale[j] : 0.
__global__ __launch_bounds__(256) void k_T2_mfma(const unsigned short* __restrict__ RNb,
                                                 const unsigned short* __restrict__ ctxB,
                                                 const int* __restrict__ cmask,
                                                 const float* __restrict__ rowscale,
                                                 const float* __restrict__ colscale,
                                                 float* __restrict__ Tpart) {
    int chunk = blockIdx.x, jt = blockIdx.y, b = blockIdx.z;
    int j0 = jt * 128;
    __shared__ unsigned short Et[128 * 40];   // [j][i] transposed E tile
    __shared__ unsigned short Bs[128 * 40];   // [h][i] ctx bf16
    __shared__ float cscArr[128];
    __shared__ int smc[256];
    int t = threadIdx.x;
    if (t < 128) cscArr[t] = colscale[b * kQ + j0 + t];
    smc[t] = cmask[b * kC + chunk * 256 + t];
    int lane = t & 63, wave = t >> 6;
    int wm = wave >> 1, wn = wave & 1;
    int lrow = lane & 15, kgrp = (lane >> 4) * 8;
    int ip = t >> 4, js = t & 15;
    int hB = t >> 1, isegB = (t & 1) * 16;

    f32x4 acc[4][4];
#pragma unroll
    for (int mt = 0; mt < 4; ++mt)
#pragma unroll
        for (int nt = 0; nt < 4; ++nt)
            acc[mt][nt] = (f32x4){0.f, 0.f, 0.f, 0.f};
    __syncthreads();

    for (int kk = 0; kk < 8; ++kk) {
        int i0 = chunk * 256 + kk * 32;
        int li = kk * 32 + 2 * ip;
        float rs0 = smc[li]     ? rowscale[b * kC + chunk * 256 + li]     : 0.f;
        float rs1 = smc[li + 1] ? rowscale[b * kC + chunk * 256 + li + 1] : 0.f;
        const unsigned short* r0 = RNb + ((size_t)b * kC + i0 + 2 * ip) * kQ + j0;
#pragma unroll
        for (int m = 0; m < 8; ++m) {
            int j = js + 16 * m;
            float c = cscArr[j];
            float e0 = bf2f(r0[j]) * rs0 * c;
            float e1 = bf2f(r0[kQ + j]) * rs1 * c;
            unsigned int pk = (unsigned int)f2bf(e0) | ((unsigned int)f2bf(e1) << 16);
            *(unsigned int*)&Et[j * 40 + 2 * ip] = pk;
        }
        {
            const unsigned short* cb = ctxB + ((size_t)b * kH + hB) * kC + i0 + isegB;
            *(bf16x8*)&Bs[hB * 40 + isegB]     = *(const bf16x8*)cb;
            *(bf16x8*)&Bs[hB * 40 + isegB + 8] = *(const bf16x8*)(cb + 8);
        }
        __syncthreads();
        bf16x8 af[4], bfr[4];
#pragma unroll
        for (int mt = 0; mt < 4; ++mt)
            af[mt] = *(const bf16x8*)&Bs[(wm * 64 + mt * 16 + lrow) * 40 + kgrp];
#pragma unroll
        for (int nt = 0; nt < 4; ++nt)
            bfr[nt] = *(const bf16x8*)&Et[(wn * 64 + nt * 16 + lrow) * 40 + kgrp];
#pragma unroll
        for (int nt = 0; nt < 4; ++nt)
#pragma unroll
            for (int mt = 0; mt < 4; ++mt)
                acc[mt][nt] = __builtin_amdgcn_mfma_f32_16x16x32_bf16(af[mt], bfr[nt], acc[mt][nt], 0, 0, 0);
        __syncthreads();
    }

    const size_t M = (size_t)kB * kH * kQ;
#pragma unroll
    for (int mt = 0; mt < 4; ++mt)
#pragma unroll
        for (int r = 0; r < 4; ++r) {
            int h = wm * 64 + mt * 16 + (lane >> 4) * 4 + r;
            float* dst = Tpart + (size_t)chunk * M + ((size_t)b * kH + h) * kQ + j0 + wn * 64 + lrow;
#pragma unroll
            for (int nt = 0; nt < 4; ++nt)
                dst[nt * 16] = acc[mt][nt][r];
        }
}

// T_bf16[b,h,j] = bf16( colinv[b,j] * sum_chunk Tpart[chunk][b,h,j] )
__global__ __launch_bounds__(256) void k_Tred(const float* __restrict__ Tpart,
                                              const float* __restrict__ colinv,
                                              unsigned short* __restrict__ Tb) {
    size_t id = (size_t)blockIdx.x * 256 + threadIdx.x;   // over B*H*Q
    const size_t M = (size_t)kB * kH * kQ;
    int j = (int)(id % kQ);
    int b = (int)(id / ((size_t)kH * kQ));
    float s = 0.f;
#pragma unroll
    for (int c = 0; c < 8; ++c) s += Tpart[c * M + id];
    Tb[id] = f2bf(s * colinv[b * kQ + j]);
}

// Output kernel: 64 i x 128 h per block. A = RNb via LDS; B fragments (qB/Tb)
// loaded directly from global (L2-hot). Epilogue in h-halves: one ctx read
// serves all four outputs.
__global__ __launch_bounds__(256) void k_out_mfma(const unsigned short* __restrict__ RNb,
                                                  const unsigned short* __restrict__ qB,
                                                  const unsigned short* __restrict__ Tb,
                                                  const float* __restrict__ ctx,
                                                  float* __restrict__ out) {
    int i0 = blockIdx.x * 64;
    int b  = blockIdx.y;
    __shared__ unsigned short As[64 * 40];
    __shared__ float stgC[64 * 68];
    __shared__ float stgT[64 * 68];
    int t = threadIdx.x;
    int rA = t >> 2, cA = (t & 3) * 8;
    int lane = t & 63, wave = t >> 6;
    int hw = wave * 32;
    int kgrp = (lane >> 4) * 8;
    int lrow = lane & 15, q4 = lane >> 4;

    f32x4 accC[4][2];
    f32x4 accT[4][2];
#pragma unroll
    for (int mt = 0; mt < 4; ++mt)
#pragma unroll
        for (int nt = 0; nt < 2; ++nt) {
            accC[mt][nt] = (f32x4){0.f, 0.f, 0.f, 0.f};
            accT[mt][nt] = (f32x4){0.f, 0.f, 0.f, 0.f};
        }

    for (int kk = 0; kk < 8; ++kk) {
        int j0 = kk * 32;
        *(bf16x8*)&As[rA * 40 + cA] =
            *(const bf16x8*)&RNb[((size_t)b * kC + i0 + rA) * kQ + j0 + cA];
        __syncthreads();
        bf16x8 af[4];
#pragma unroll
        for (int mt = 0; mt < 4; ++mt)
            af[mt] = *(const bf16x8*)&As[(mt * 16 + lrow) * 40 + kgrp];
#pragma unroll
        for (int nt = 0; nt < 2; ++nt) {
            int h = hw + nt * 16 + lrow;
            bf16x8 bq = *(const bf16x8*)&qB[((size_t)b * kH + h) * kQ + j0 + kgrp];
            bf16x8 bt = *(const bf16x8*)&Tb[((size_t)b * kH + h) * kQ + j0 + kgrp];
#pragma unroll
            for (int mt = 0; mt < 4; ++mt) {
                accC[mt][nt] = __builtin_amdgcn_mfma_f32_16x16x32_bf16(af[mt], bq, accC[mt][nt], 0, 0, 0);
                accT[mt][nt] = __builtin_amdgcn_mfma_f32_16x16x32_bf16(af[mt], bt, accT[mt][nt], 0, 0, 0);
            }
        }
        __syncthreads();
    }

    const size_t N = (size_t)kB * kH * kC;
    int ii = t & 63, hb = t >> 6;
#pragma unroll
    for (int g = 0; g < 2; ++g) {
        if ((wave >> 1) == g) {
            int hloc = (wave & 1) * 32;
#pragma unroll
            for (int mt = 0; mt < 4; ++mt)
#pragma unroll
                for (int nt = 0; nt < 2; ++nt)
#pragma unroll
                    for (int r = 0; r < 4; ++r) {
                        int rowh = hloc + nt * 16 + lrow;
                        int coli = mt * 16 + q4 * 4 + r;
                        stgC[rowh * 68 + coli] = accC[mt][nt][r];
                        stgT[rowh * 68 + coli] = accT[mt][nt][r];
                    }
        }
        __syncthreads();
#pragma unroll 4
        for (int p = 0; p < 16; ++p) {
            int hl = hb + p * 4;
            int h = g * 64 + hl;
            float vc = stgC[hl * 68 + ii];
            float vt = stgT[hl * 68 + ii];
            size_t base = ((size_t)b * kH + h) * kC + i0 + ii;
            float c = ctx[base];
            out[base]         = c;
            out[N + base]     = vc;
            out[2 * N + base] = c * vc;
            out[3 * N + base] = c * vt;
        }
        __syncthreads();
    }
}

extern "C" void kernel_launch(void* const* d_in, const int* in_sizes, int n_in,
                              void* d_out, int out_size, void* d_ws, size_t ws_size,
                              hipStream_t stream) {
    const float* ctx   = (const float*)d_in[0];
    const float* q     = (const float*)d_in[1];
    const int*   cmask = (const int*)d_in[2];
    const int*   qmask = (const int*)d_in[3];
    const float* w_c   = (const float*)d_in[4];
    const float* w_q   = (const float*)d_in[5];
    const float* w_cq  = (const float*)d_in[6];
    const float* bias  = (const float*)d_in[7];
    float* out = (float*)d_out;

    // Workspace (~100 MB of 512 MiB).
    unsigned short* RNb  = (unsigned short*)d_ws;                 // B*C*Q bf16
    unsigned short* ctxB = RNb + (size_t)kB * kC * kQ;            // B*H*C bf16
    unsigned short* qB   = ctxB + (size_t)kB * kH * kC;           // B*H*Q bf16
    unsigned short* Tb   = qB + (size_t)kB * kH * kQ;             // B*H*Q bf16
    float* part_c   = (float*)(Tb + (size_t)kB * kH * kQ);        // B*C
    float* part_q   = part_c + kB * kC;                           // B*Q
    float* rowscale = part_q + kB * kQ;                           // B*C
    float* colscale = rowscale + kB * kC;                         // B*Q
    float* colinv   = colscale + kB * kQ;                         // B*Q
    float* pm       = colinv + kB * kQ;                           // B*128*Q
    float* ps       = pm + (size_t)kB * kColChunks * kQ;          // B*128*Q
    size_t need = (size_t)((char*)(ps + (size_t)kB * kColChunks * kQ) - (char*)d_ws);
    if (ws_size < need) return;

    // d_out scratch (consumed before k_out_mfma writes):
    //   [0, N) floats      : Tpart (8 * B*H*Q f32)
    //   [2N, 2.5N) floats  : ctxW (B*C*H bf16)
    //   then qT            : (B*Q*H bf16)
    const size_t N = (size_t)kB * kH * kC;
    float* Tpart = out;
    unsigned short* ctxW = (unsigned short*)(out + 2 * N);
    unsigned short* qT   = ctxW + (size_t)kB * kC * kH;

    k_prep_c<<<dim3(kC / 64, kB), 256, 0, stream>>>(ctx, w_c, w_cq, ctxW, ctxB, part_c);
    k_prep_q<<<dim3(kQ / 64, kB), 256, 0, stream>>>(q, w_q, qT, qB, part_q);
    k_Ssoft<<<dim3(kC / 64, kB), 256, 0, stream>>>(ctxW, qT, part_c, part_q, bias,
                                                   qmask, cmask, RNb, rowscale, pm, ps);
    k_colcombine<<<kB * kQ / 256, 256, 0, stream>>>(pm, ps, colscale, colinv);
    k_T2_mfma<<<dim3(8, 2, kB), 256, 0, stream>>>(RNb, ctxB, cmask, rowscale, colscale, Tpart);
    k_Tred<<<kB * kH * kQ / 256, 256, 0, stream>>>(Tpart, colinv, Tb);
    k_out_mfma<<<dim3(kC / 64, kB), 256, 0, stream>>>(RNb, qB, Tb, ctx, out);
}

// Round 8
// 119.288 us; speedup vs baseline: 2.1291x; 1.6122x over previous
//
#include <hip/hip_runtime.h>
#include <hip/hip_bf16.h>
#include <math.h>

// QANet Context-Query attention. B=32 H=128 C=2048 Q=256.
// R7: column-softmax max eliminated algebraically: colZ_j = sum_i cmask_i *
//     RN_ij * rowscale_i  (exp(S)=RN*rowscale identity). Ssoft epilogue is
//     exp-free on the column side; T2 stages E' = RN*rowscale (1 mul), reads
//     ctx fp32 directly (ctxB deleted). colinv = 1/colZ with 0-guard.

constexpr int kB = 32, kH = 128, kC = 2048, kQ = 256;
constexpr int kColChunks = 128;          // (kC/64) blocks * 4 waves
constexpr float kNEG = -1e30f;

typedef short bf16x8 __attribute__((ext_vector_type(8)));
typedef float f32x4 __attribute__((ext_vector_type(4)));

static __device__ __forceinline__ unsigned short f2bf(float f) {
    __hip_bfloat16 h = __float2bfloat16(f);
    return __builtin_bit_cast(unsigned short, h);
}
static __device__ __forceinline__ float bf2f(unsigned short u) {
    unsigned int x = ((unsigned int)u) << 16;
    return __builtin_bit_cast(float, x);
}

// One ctx read -> ctxW[b,i,h]=bf16(ctx*w_cq) and part_c.
__global__ __launch_bounds__(256) void k_prep_c(const float* __restrict__ ctx,
                                                const float* __restrict__ w_c,
                                                const float* __restrict__ w_cq,
                                                unsigned short* __restrict__ ctxW,
                                                float* __restrict__ part_c) {
    int i0 = blockIdx.x * 64, b = blockIdx.y;
    __shared__ unsigned short tile[64 * 136];
    __shared__ float pcp[4][64];
    int t = threadIdx.x;
    int il = t & 63, hg = t >> 6, hb = hg * 2;
    float accc = 0.f;
#pragma unroll
    for (int r = 0; r < 16; ++r) {
        int h = r * 8 + hb;
        float v0 = ctx[((size_t)b * kH + h) * kC + i0 + il];
        float v1 = ctx[((size_t)b * kH + h + 1) * kC + i0 + il];
        accc += v0 * w_c[h] + v1 * w_c[h + 1];
        unsigned int pk = (unsigned int)f2bf(v0 * w_cq[h]) |
                          ((unsigned int)f2bf(v1 * w_cq[h + 1]) << 16);
        *(unsigned int*)&tile[il * 136 + h] = pk;
    }
    pcp[hg][il] = accc;
    __syncthreads();
    if (t < 64) part_c[b * kC + i0 + t] = pcp[0][t] + pcp[1][t] + pcp[2][t] + pcp[3][t];
#pragma unroll
    for (int r = 0; r < 4; ++r) {
        int idx = r * 256 + t;
        int i = idx >> 4, hc = (idx & 15) * 8;
        *(bf16x8*)&ctxW[((size_t)b * kC + i0 + i) * kH + hc] =
            *(const bf16x8*)&tile[i * 136 + hc];
    }
}

// One q read -> qT[b,j,h]=bf16(q), qB[b,h,j]=bf16(q), part_q.
__global__ __launch_bounds__(256) void k_prep_q(const float* __restrict__ q,
                                                const float* __restrict__ w_q,
                                                unsigned short* __restrict__ qT,
                                                unsigned short* __restrict__ qB,
                                                float* __restrict__ part_q) {
    int j0 = blockIdx.x * 64, b = blockIdx.y;
    __shared__ unsigned short tile[64 * 136];
    __shared__ float pcp[4][64];
    int t = threadIdx.x;
    int jl = t & 63, hg = t >> 6, hb = hg * 2;
    float accq = 0.f;
#pragma unroll
    for (int r = 0; r < 16; ++r) {
        int h = r * 8 + hb;
        float v0 = q[((size_t)b * kH + h) * kQ + j0 + jl];
        float v1 = q[((size_t)b * kH + h + 1) * kQ + j0 + jl];
        accq += v0 * w_q[h] + v1 * w_q[h + 1];
        qB[((size_t)b * kH + h) * kQ + j0 + jl]     = f2bf(v0);
        qB[((size_t)b * kH + h + 1) * kQ + j0 + jl] = f2bf(v1);
        unsigned int pk = (unsigned int)f2bf(v0) | ((unsigned int)f2bf(v1) << 16);
        *(unsigned int*)&tile[jl * 136 + h] = pk;
    }
    pcp[hg][jl] = accq;
    __syncthreads();
    if (t < 64) part_q[b * kQ + j0 + t] = pcp[0][t] + pcp[1][t] + pcp[2][t] + pcp[3][t];
#pragma unroll
    for (int r = 0; r < 4; ++r) {
        int idx = r * 256 + t;
        int j = idx >> 4, hc = (idx & 15) * 8;
        *(bf16x8*)&qT[((size_t)b * kQ + j0 + j) * kH + hc] =
            *(const bf16x8*)&tile[j * 136 + hc];
    }
}

// Fused S + softmax. Block = 64 i x 256 j; wave = 16 i x 256 j.
// Writes RNb, rowscale = rowsum*e^rowmax, and column partial sums
// cs_j = sum_{i in chunk, cmask} exp(S_ij)  (exp-free via e*e^rmax).
__global__ __launch_bounds__(256) void k_Ssoft(const unsigned short* __restrict__ ctxW,
                                               const unsigned short* __restrict__ qT,
                                               const float* __restrict__ part_c,
                                               const float* __restrict__ part_q,
                                               const float* __restrict__ bias,
                                               const int* __restrict__ qmask,
                                               const int* __restrict__ cmask,
                                               unsigned short* __restrict__ RNb,
                                               float* __restrict__ rowscale,
                                               float* __restrict__ ps) {
    int i0 = blockIdx.x * 64, b = blockIdx.y;
    __shared__ unsigned short As[64 * 40];
    __shared__ unsigned short Bs[256 * 40];
    __shared__ float smpq[256];
    __shared__ int smqm[256];
    int t = threadIdx.x;
    int lane = t & 63, w = t >> 6;
    int lrow = lane & 15, q4 = lane >> 4, kgrp = q4 * 8;
    smpq[t] = part_q[b * kQ + t];
    smqm[t] = qmask[b * kQ + t];

    f32x4 acc[16];
#pragma unroll
    for (int nt = 0; nt < 16; ++nt) acc[nt] = (f32x4){0.f, 0.f, 0.f, 0.f};

    for (int kk = 0; kk < 4; ++kk) {
        int h0 = kk * 32;
        {
            int iA = t >> 2, hcA = (t & 3) * 8;
            *(bf16x8*)&As[iA * 40 + hcA] =
                *(const bf16x8*)&ctxW[((size_t)b * kC + i0 + iA) * kH + h0 + hcA];
        }
#pragma unroll
        for (int r2 = 0; r2 < 4; ++r2) {
            int idx = r2 * 256 + t;
            int jB = idx >> 2, hcB = (idx & 3) * 8;
            *(bf16x8*)&Bs[jB * 40 + hcB] =
                *(const bf16x8*)&qT[((size_t)b * kQ + jB) * kH + h0 + hcB];
        }
        __syncthreads();
        bf16x8 af = *(const bf16x8*)&As[(w * 16 + lrow) * 40 + kgrp];
#pragma unroll
        for (int nt = 0; nt < 16; ++nt) {
            bf16x8 bf = *(const bf16x8*)&Bs[(nt * 16 + lrow) * 40 + kgrp];
            acc[nt] = __builtin_amdgcn_mfma_f32_16x16x32_bf16(af, bf, acc[nt], 0, 0, 0);
        }
        __syncthreads();
    }

    // ---- epilogue: parts + row softmax + column partial sums ----
    float bs = bias[0];
    float pq[16];
    int qm[16];
#pragma unroll
    for (int nt = 0; nt < 16; ++nt) {
        int col = nt * 16 + lrow;
        pq[nt] = smpq[col];
        qm[nt] = smqm[col];
    }
    int rowbase = i0 + w * 16 + q4 * 4;
    float pc[4];
    int cmr[4];
#pragma unroll
    for (int r = 0; r < 4; ++r) {
        pc[r] = part_c[b * kC + rowbase + r] + bs;
        cmr[r] = cmask[b * kC + rowbase + r];
    }
#pragma unroll
    for (int nt = 0; nt < 16; ++nt)
#pragma unroll
        for (int r = 0; r < 4; ++r)
            acc[nt][r] += pc[r] + pq[nt];

    float cs[16];
#pragma unroll
    for (int nt = 0; nt < 16; ++nt) cs[nt] = 0.f;

#pragma unroll
    for (int r = 0; r < 4; ++r) {
        float rmax = kNEG;
#pragma unroll
        for (int nt = 0; nt < 16; ++nt)
            if (qm[nt]) rmax = fmaxf(rmax, acc[nt][r]);
        rmax = fmaxf(rmax, __shfl_xor(rmax, 1));
        rmax = fmaxf(rmax, __shfl_xor(rmax, 2));
        rmax = fmaxf(rmax, __shfl_xor(rmax, 4));
        rmax = fmaxf(rmax, __shfl_xor(rmax, 8));
        float e[16];
        float rsum = 0.f;
#pragma unroll
        for (int nt = 0; nt < 16; ++nt) {
            e[nt] = qm[nt] ? __expf(acc[nt][r] - rmax) : 0.f;
            rsum += e[nt];
        }
        rsum += __shfl_xor(rsum, 1);
        rsum += __shfl_xor(rsum, 2);
        rsum += __shfl_xor(rsum, 4);
        rsum += __shfl_xor(rsum, 8);
        float rinv = 1.f / rsum;
        float emax = __expf(rmax);
        unsigned short* dst = RNb + ((size_t)b * kC + rowbase + r) * kQ;
#pragma unroll
        for (int nt = 0; nt < 16; ++nt)
            dst[nt * 16 + lrow] = f2bf(e[nt] * rinv);
        if (lrow == 0)
            rowscale[b * kC + rowbase + r] = rsum * emax;
        if (cmr[r]) {
#pragma unroll
            for (int nt = 0; nt < 16; ++nt)
                cs[nt] += e[nt] * emax;       // = exp(S_ij), exact
        }
    }
    // plain-sum combine across the 4 lane-quarters (different rows, same cols)
#pragma unroll
    for (int nt = 0; nt < 16; ++nt) {
        cs[nt] += __shfl_xor(cs[nt], 16);
        cs[nt] += __shfl_xor(cs[nt], 32);
    }
    int chunk = blockIdx.x * 4 + w;
#pragma unroll
    for (int k = 0; k < 4; ++k) {
        int nt = q4 * 4 + k;
        int col = nt * 16 + lrow;
        ps[((size_t)b * kColChunks + chunk) * kQ + col] = cs[nt];
    }
}

// colinv = 1/colZ (0 if colZ==0, i.e. fully-masked column: harmless, RN=0 there).
__global__ __launch_bounds__(256) void k_colZ(const float* __restrict__ ps,
                                              float* __restrict__ colinv) {
    int id = blockIdx.x * 256 + threadIdx.x;   // over B*Q
    int b = id / kQ, j = id % kQ;
    float s = 0.f;
#pragma unroll 8
    for (int c = 0; c < kColChunks; ++c)
        s += ps[((size_t)b * kColChunks + c) * kQ + j];
    colinv[id] = s > 0.f ? 1.f / s : 0.f;
}

// T partials via MFMA. E'[i,j] = cmask[i] ? RN[i,j]*rowscale[i] : 0 (= exp(S)).
// A = ctx (fp32 staged -> bf16), B = E'^T (transposed LDS staging).
__global__ __launch_bounds__(256) void k_T2_mfma(const unsigned short* __restrict__ RNb,
                                                 const float* __restrict__ ctx,
                                                 const int* __restrict__ cmask,
                                                 const float* __restrict__ rowscale,
                                                 float* __restrict__ Tpart) {
    int chunk = blockIdx.x, jt = blockIdx.y, b = blockIdx.z;
    int j0 = jt * 128;
    __shared__ unsigned short Et[128 * 40];   // [j][i] transposed E' tile
    __shared__ unsigned short Bs[128 * 40];   // [h][i] ctx bf16
    __shared__ int smc[256];
    int t = threadIdx.x;
    smc[t] = cmask[b * kC + chunk * 256 + t];
    int lane = t & 63, wave = t >> 6;
    int wm = wave >> 1, wn = wave & 1;
    int lrow = lane & 15, kgrp = (lane >> 4) * 8;
    int ip = t >> 4, js = t & 15;
    int hB = t >> 1, isegB = (t & 1) * 16;

    f32x4 acc[4][4];
#pragma unroll
    for (int mt = 0; mt < 4; ++mt)
#pragma unroll
        for (int nt = 0; nt < 4; ++nt)
            acc[mt][nt] = (f32x4){0.f, 0.f, 0.f, 0.f};
    __syncthreads();

    for (int kk = 0; kk < 8; ++kk) {
        int i0 = chunk * 256 + kk * 32;
        int li = kk * 32 + 2 * ip;
        float rs0 = smc[li]     ? rowscale[b * kC + chunk * 256 + li]     : 0.f;
        float rs1 = smc[li + 1] ? rowscale[b * kC + chunk * 256 + li + 1] : 0.f;
        const unsigned short* r0 = RNb + ((size_t)b * kC + i0 + 2 * ip) * kQ + j0;
#pragma unroll
        for (int m = 0; m < 8; ++m) {
            int j = js + 16 * m;
            float e0 = bf2f(r0[j]) * rs0;
            float e1 = bf2f(r0[kQ + j]) * rs1;
            unsigned int pk = (unsigned int)f2bf(e0) | ((unsigned int)f2bf(e1) << 16);
            *(unsigned int*)&Et[j * 40 + 2 * ip] = pk;
        }
        {   // A: ctx fp32 -> bf16, rows h, 32-i segment
            const float* cb = ctx + ((size_t)b * kH + hB) * kC + i0 + isegB;
            float4 a0 = *(const float4*)cb;
            float4 a1 = *(const float4*)(cb + 4);
            float4 a2 = *(const float4*)(cb + 8);
            float4 a3 = *(const float4*)(cb + 12);
            float vv[16] = {a0.x, a0.y, a0.z, a0.w, a1.x, a1.y, a1.z, a1.w,
                            a2.x, a2.y, a2.z, a2.w, a3.x, a3.y, a3.z, a3.w};
            bf16x8 p0, p1;
#pragma unroll
            for (int e = 0; e < 8; ++e) {
                p0[e] = (short)f2bf(vv[e]);
                p1[e] = (short)f2bf(vv[8 + e]);
            }
            *(bf16x8*)&Bs[hB * 40 + isegB]     = p0;
            *(bf16x8*)&Bs[hB * 40 + isegB + 8] = p1;
        }
        __syncthreads();
        bf16x8 af[4], bfr[4];
#pragma unroll
        for (int mt = 0; mt < 4; ++mt)
            af[mt] = *(const bf16x8*)&Bs[(wm * 64 + mt * 16 + lrow) * 40 + kgrp];
#pragma unroll
        for (int nt = 0; nt < 4; ++nt)
            bfr[nt] = *(const bf16x8*)&Et[(wn * 64 + nt * 16 + lrow) * 40 + kgrp];
#pragma unroll
        for (int nt = 0; nt < 4; ++nt)
#pragma unroll
            for (int mt = 0; mt < 4; ++mt)
                acc[mt][nt] = __builtin_amdgcn_mfma_f32_16x16x32_bf16(af[mt], bfr[nt], acc[mt][nt], 0, 0, 0);
        __syncthreads();
    }

    const size_t M = (size_t)kB * kH * kQ;
#pragma unroll
    for (int mt = 0; mt < 4; ++mt)
#pragma unroll
        for (int r = 0; r < 4; ++r) {
            int h = wm * 64 + mt * 16 + (lane >> 4) * 4 + r;
            float* dst = Tpart + (size_t)chunk * M + ((size_t)b * kH + h) * kQ + j0 + wn * 64 + lrow;
#pragma unroll
            for (int nt = 0; nt < 4; ++nt)
                dst[nt * 16] = acc[mt][nt][r];
        }
}

// T_bf16[b,h,j] = bf16( colinv[b,j] * sum_chunk Tpart[chunk][b,h,j] )
__global__ __launch_bounds__(256) void k_Tred(const float* __restrict__ Tpart,
                                              const float* __restrict__ colinv,
                                              unsigned short* __restrict__ Tb) {
    size_t id = (size_t)blockIdx.x * 256 + threadIdx.x;   // over B*H*Q
    const size_t M = (size_t)kB * kH * kQ;
    int j = (int)(id % kQ);
    int b = (int)(id / ((size_t)kH * kQ));
    float s = 0.f;
#pragma unroll
    for (int c = 0; c < 8; ++c) s += Tpart[c * M + id];
    Tb[id] = f2bf(s * colinv[b * kQ + j]);
}

// Output kernel: 64 i x 128 h per block. A = RNb via LDS; B fragments (qB/Tb)
// direct from global (L2-hot). Epilogue in h-halves: one ctx read, 4 outputs.
__global__ __launch_bounds__(256) void k_out_mfma(const unsigned short* __restrict__ RNb,
                                                  const unsigned short* __restrict__ qB,
                                                  const unsigned short* __restrict__ Tb,
                                                  const float* __restrict__ ctx,
                                                  float* __restrict__ out) {
    int i0 = blockIdx.x * 64;
    int b  = blockIdx.y;
    __shared__ unsigned short As[64 * 40];
    __shared__ float stgC[64 * 68];
    __shared__ float stgT[64 * 68];
    int t = threadIdx.x;
    int rA = t >> 2, cA = (t & 3) * 8;
    int lane = t & 63, wave = t >> 6;
    int hw = wave * 32;
    int kgrp = (lane >> 4) * 8;
    int lrow = lane & 15, q4 = lane >> 4;

    f32x4 accC[4][2];
    f32x4 accT[4][2];
#pragma unroll
    for (int mt = 0; mt < 4; ++mt)
#pragma unroll
        for (int nt = 0; nt < 2; ++nt) {
            accC[mt][nt] = (f32x4){0.f, 0.f, 0.f, 0.f};
            accT[mt][nt] = (f32x4){0.f, 0.f, 0.f, 0.f};
        }

    for (int kk = 0; kk < 8; ++kk) {
        int j0 = kk * 32;
        *(bf16x8*)&As[rA * 40 + cA] =
            *(const bf16x8*)&RNb[((size_t)b * kC + i0 + rA) * kQ + j0 + cA];
        __syncthreads();
        bf16x8 af[4];
#pragma unroll
        for (int mt = 0; mt < 4; ++mt)
            af[mt] = *(const bf16x8*)&As[(mt * 16 + lrow) * 40 + kgrp];
#pragma unroll
        for (int nt = 0; nt < 2; ++nt) {
            int h = hw + nt * 16 + lrow;
            bf16x8 bq = *(const bf16x8*)&qB[((size_t)b * kH + h) * kQ + j0 + kgrp];
            bf16x8 bt = *(const bf16x8*)&Tb[((size_t)b * kH + h) * kQ + j0 + kgrp];
#pragma unroll
            for (int mt = 0; mt < 4; ++mt) {
                accC[mt][nt] = __builtin_amdgcn_mfma_f32_16x16x32_bf16(af[mt], bq, accC[mt][nt], 0, 0, 0);
                accT[mt][nt] = __builtin_amdgcn_mfma_f32_16x16x32_bf16(af[mt], bt, accT[mt][nt], 0, 0, 0);
            }
        }
        __syncthreads();
    }

    const size_t N = (size_t)kB * kH * kC;
    int ii = t & 63, hb = t >> 6;
#pragma unroll
    for (int g = 0; g < 2; ++g) {
        if ((wave >> 1) == g) {
            int hloc = (wave & 1) * 32;
#pragma unroll
            for (int mt = 0; mt < 4; ++mt)
#pragma unroll
                for (int nt = 0; nt < 2; ++nt)
#pragma unroll
                    for (int r = 0; r < 4; ++r) {
                        int rowh = hloc + nt * 16 + lrow;
                        int coli = mt * 16 + q4 * 4 + r;
                        stgC[rowh * 68 + coli] = accC[mt][nt][r];
                        stgT[rowh * 68 + coli] = accT[mt][nt][r];
                    }
        }
        __syncthreads();
#pragma unroll 4
        for (int p = 0; p < 16; ++p) {
            int hl = hb + p * 4;
            int h = g * 64 + hl;
            float vc = stgC[hl * 68 + ii];
            float vt = stgT[hl * 68 + ii];
            size_t base = ((size_t)b * kH + h) * kC + i0 + ii;
            float c = ctx[base];
            out[base]         = c;
            out[N + base]     = vc;
            out[2 * N + base] = c * vc;
            out[3 * N + base] = c * vt;
        }
        __syncthreads();
    }
}

extern "C" void kernel_launch(void* const* d_in, const int* in_sizes, int n_in,
                              void* d_out, int out_size, void* d_ws, size_t ws_size,
                              hipStream_t stream) {
    const float* ctx   = (const float*)d_in[0];
    const float* q     = (const float*)d_in[1];
    const int*   cmask = (const int*)d_in[2];
    const int*   qmask = (const int*)d_in[3];
    const float* w_c   = (const float*)d_in[4];
    const float* w_q   = (const float*)d_in[5];
    const float* w_cq  = (const float*)d_in[6];
    const float* bias  = (const float*)d_in[7];
    float* out = (float*)d_out;

    // Workspace (~42 MB of 512 MiB).
    unsigned short* RNb = (unsigned short*)d_ws;                  // B*C*Q bf16
    unsigned short* qB  = RNb + (size_t)kB * kC * kQ;             // B*H*Q bf16
    unsigned short* Tb  = qB + (size_t)kB * kH * kQ;              // B*H*Q bf16
    float* part_c   = (float*)(Tb + (size_t)kB * kH * kQ);        // B*C
    float* part_q   = part_c + kB * kC;                           // B*Q
    float* rowscale = part_q + kB * kQ;                           // B*C
    float* colinv   = rowscale + kB * kC;                         // B*Q
    float* ps       = colinv + kB * kQ;                           // B*128*Q
    size_t need = (size_t)((char*)(ps + (size_t)kB * kColChunks * kQ) - (char*)d_ws);
    if (ws_size < need) return;

    // d_out scratch (consumed before k_out_mfma writes):
    //   [0, N) floats      : Tpart (8 * B*H*Q f32)
    //   [2N, 2.5N) floats  : ctxW (B*C*H bf16)
    //   then qT            : (B*Q*H bf16)
    const size_t N = (size_t)kB * kH * kC;
    float* Tpart = out;
    unsigned short* ctxW = (unsigned short*)(out + 2 * N);
    unsigned short* qT   = ctxW + (size_t)kB * kC * kH;

    k_prep_c<<<dim3(kC / 64, kB), 256, 0, stream>>>(ctx, w_c, w_cq, ctxW, part_c);
    k_prep_q<<<dim3(kQ / 64, kB), 256, 0, stream>>>(q, w_q, qT, qB, part_q);
    k_Ssoft<<<dim3(kC / 64, kB), 256, 0, stream>>>(ctxW, qT, part_c, part_q, bias,
                                                   qmask, cmask, RNb, rowscale, ps);
    k_colZ<<<kB * kQ / 256, 256, 0, stream>>>(ps, colinv);
    k_T2_mfma<<<dim3(8, 2, kB), 256, 0, stream>>>(RNb, ctx, cmask, rowscale, Tpart);
    k_Tred<<<kB * kH * kQ / 256, 256, 0, stream>>>(Tpart, colinv, Tb);
    k_out_mfma<<<dim3(kC / 64, kB), 256, 0, stream>>>(RNb, qB, Tb, ctx, out);
}